// Round 7
// baseline (136.913 us; speedup 1.0000x reference)
//
#include <hip/hip_runtime.h>

#define BATCH 4
#define NPTS 8192
#define DIM 128
#define TOTAL_ROWS (BATCH * NPTS)   // 32768
#define SLICES 2
#define SLICE_W 4096
#define ITERS 64                    // 16-col tiles per wave (wave strides 64 cols)
#define TILES_PER_B 512
#define TILE_US 2048                // ushorts per packed 16-col tile (4 KB)

typedef __attribute__((ext_vector_type(8))) short bf16x8;
typedef __attribute__((ext_vector_type(4))) float f32x4;

// fp32 -> bf16 round-to-nearest-even
__device__ __forceinline__ unsigned short f2bf(float x) {
  unsigned u = __float_as_uint(x);
  u += 0x7FFFu + ((u >> 16) & 1u);
  return (unsigned short)(u >> 16);
}
// monotonic encoding of float for unsigned atomicMin (handles negatives)
__device__ __forceinline__ unsigned encf(float f) {
  unsigned b = __float_as_uint(f);
  return (b & 0x80000000u) ? ~b : (b | 0x80000000u);
}
__device__ __forceinline__ float decf(unsigned u) {
  unsigned b = (u & 0x80000000u) ? (u ^ 0x80000000u) : ~u;
  return __uint_as_float(b);
}

// ---- pack f_ into MFMA-fragment order (bf16) + row norms gn2 ----
// one block per 16-col tile; fragment uint4 index within tile = tid_l = [kc|q|l15]
__global__ void pack_b_kernel(const float* __restrict__ in,
                              unsigned short* __restrict__ pk,
                              float* __restrict__ gn2) {
  __shared__ float sred[16][17];
  int tl  = threadIdx.x;
  int l15 = tl & 15, q = (tl >> 4) & 3, kc = tl >> 6;
  int tile = blockIdx.x;                 // b*512 + mtg
  int b = tile >> 9, mtg = tile & 511;
  const float* src = in + ((size_t)(b * NPTS + mtg * 16 + l15) * DIM) + kc * 32 + q * 8;
  float4 x = ((const float4*)src)[0], y = ((const float4*)src)[1];
  union { unsigned short us[8]; uint4 u4; } p;
  p.us[0] = f2bf(x.x); p.us[1] = f2bf(x.y); p.us[2] = f2bf(x.z); p.us[3] = f2bf(x.w);
  p.us[4] = f2bf(y.x); p.us[5] = f2bf(y.y); p.us[6] = f2bf(y.z); p.us[7] = f2bf(y.w);
  ((uint4*)(pk + (size_t)tile * TILE_US))[tl] = p.u4;
  float s = 0.f;
  s = fmaf(x.x, x.x, s); s = fmaf(x.y, x.y, s);
  s = fmaf(x.z, x.z, s); s = fmaf(x.w, x.w, s);
  s = fmaf(y.x, y.x, s); s = fmaf(y.y, y.y, s);
  s = fmaf(y.z, y.z, s); s = fmaf(y.w, y.w, s);
  sred[l15][(kc << 2) | q] = s;
  __syncthreads();
  if (tl < 16) {
    float t = 0.f;
    #pragma unroll
    for (int j = 0; j < 16; ++j) t += sred[tl][j];
    gn2[tile * 16 + tl] = t;             // row = b*NPTS + mtg*16 + tl
  }
}

// ---- main: block = 4 waves x SAME 64 rows; wave owns cols widx*16 + j*64 ----
// per-wave private 3-deep LDS ring staged by global_load_lds; NO barriers in loop
__global__ __launch_bounds__(256, 3)
void chamfer_mfma_kernel(const float* __restrict__ f,
                         const unsigned short* __restrict__ pk,
                         const float* __restrict__ gn2,
                         unsigned int* __restrict__ rowmin,
                         unsigned int* __restrict__ colmin) {
  const int lane = threadIdx.x & 63;
  const int l15  = lane & 15;
  const int q    = lane >> 4;                 // 0..3
  const int widx = threadIdx.x >> 6;          // 0..3

  // 8 (b,slice) combos map 1:1 onto the 8 XCDs (bid%8 round-robin)
  const int bid   = blockIdx.x;               // 0..1023
  const int combo = bid & 7;
  const int b     = combo >> 1;
  const int slice = combo & 1;
  const int rgrp  = bid >> 3;                 // 0..127
  const int r0    = rgrp * 64;
  const int bN    = b * NPTS;

  // ring: [slot 0..2][wave 0..3][2176 us] = 52224 B (frag 2048 us + gn tail 128 us)
  __shared__ unsigned short ring_s[3 * 4 * 2176];
  unsigned short* myring = &ring_s[widx * 2176];

  // ---- A fragments (4 tiles x 4 k-chunks) + seeds h = -fn2/2, in-flight ----
  bf16x8 af[4][4];
  float h[4][4];
  const float* fb = f + (size_t)bN * DIM;
  #pragma unroll
  for (int t = 0; t < 4; ++t) {
    const float* frow = fb + (size_t)(r0 + t * 16 + l15) * DIM + q * 8;
    float s = 0.f;
    #pragma unroll
    for (int kc = 0; kc < 4; ++kc) {
      float4 x = *(const float4*)(frow + kc * 32);
      float4 y = *(const float4*)(frow + kc * 32 + 4);
      bf16x8 v;
      v[0] = (short)f2bf(x.x); v[1] = (short)f2bf(x.y);
      v[2] = (short)f2bf(x.z); v[3] = (short)f2bf(x.w);
      v[4] = (short)f2bf(y.x); v[5] = (short)f2bf(y.y);
      v[6] = (short)f2bf(y.z); v[7] = (short)f2bf(y.w);
      af[t][kc] = v;
      s = fmaf(x.x, x.x, s); s = fmaf(x.y, x.y, s);
      s = fmaf(x.z, x.z, s); s = fmaf(x.w, x.w, s);
      s = fmaf(y.x, y.x, s); s = fmaf(y.y, y.y, s);
      s = fmaf(y.z, y.z, s); s = fmaf(y.w, y.w, s);
    }
    s += __shfl_xor(s, 16); s += __shfl_xor(s, 32);  // lane holds fn2 of row (l&15)
    #pragma unroll
    for (int i = 0; i < 4; ++i) h[t][i] = -0.5f * __shfl(s, (q << 2) + i);
  }

  float rowmax[4][4];
  #pragma unroll
  for (int t = 0; t < 4; ++t)
    #pragma unroll
    for (int i = 0; i < 4; ++i) rowmax[t][i] = -3.4e38f;

  // wave's tile for iter j: batch-tile index = slice*256 + j*4 + widx
  const unsigned short* pkb = pk + (size_t)(b * TILES_PER_B + slice * 256 + widx) * TILE_US;
  const float* gnb = gn2 + bN + slice * SLICE_W + widx * 16;

  auto stage = [&](int j, int slot) {
    const unsigned short* g = pkb + (size_t)j * 4 * TILE_US;
    unsigned short* lb = myring + slot * (4 * 2176);
    #pragma unroll
    for (int kc = 0; kc < 4; ++kc)
      __builtin_amdgcn_global_load_lds(
          (const __attribute__((address_space(1))) void*)(g + kc * 512 + lane * 8),
          (__attribute__((address_space(3))) void*)(lb + kc * 512),
          16, 0, 0);
    __builtin_amdgcn_global_load_lds(
        (const __attribute__((address_space(1))) void*)(gnb + j * 64 + (lane & 15)),
        (__attribute__((address_space(3))) void*)(lb + 2048),
        4, 0, 0);
  };

  auto doTile = [&](int j, int slot) {
    const unsigned short* lb = myring + slot * (4 * 2176);
    bf16x8 bfr[4];
    #pragma unroll
    for (int kc = 0; kc < 4; ++kc)
      bfr[kc] = *(const bf16x8*)(lb + kc * 512 + lane * 8);
    float g2v = -0.5f * ((const float*)(lb + 2048))[lane];  // lane's own staged copy = gn2[m0+l15]

    f32x4 acc[4];
    #pragma unroll
    for (int t = 0; t < 4; ++t) {
      f32x4 a;
      a[0] = h[t][0] + g2v; a[1] = h[t][1] + g2v;
      a[2] = h[t][2] + g2v; a[3] = h[t][3] + g2v;
      #pragma unroll
      for (int kc = 0; kc < 4; ++kc)
        a = __builtin_amdgcn_mfma_f32_16x16x32_bf16(af[t][kc], bfr[kc], a, 0, 0, 0);
      acc[t] = a;
    }
    // acc = dot - (fn2+gn2)/2 = -dis/2  ->  dis = -2*acc; min dis = -2*max acc
    float cmax = -3.4e38f;
    #pragma unroll
    for (int t = 0; t < 4; ++t)
      #pragma unroll
      for (int i = 0; i < 4; ++i) {
        rowmax[t][i] = fmaxf(rowmax[t][i], acc[t][i]);
        cmax = fmaxf(cmax, acc[t][i]);
      }
    cmax = fmaxf(cmax, __shfl_xor(cmax, 16));
    cmax = fmaxf(cmax, __shfl_xor(cmax, 32));
    if (lane < 16)
      atomicMin(&colmin[bN + slice * SLICE_W + j * 64 + widx * 16 + lane],
                encf(-2.f * cmax));
  };

  // prologue: 2 tiles in flight
  stage(0, 0);
  stage(1, 1);
  // main loop: issue j+2, ensure j resident (all but newest 2 stages = 10 loads)
  int slot2 = 2, slot0 = 0;
  for (int j = 0; j < ITERS - 2; ++j) {
    stage(j + 2, slot2);
    asm volatile("s_waitcnt vmcnt(10)" ::: "memory");
    doTile(j, slot0);
    if (++slot2 >= 3) slot2 = 0;
    if (++slot0 >= 3) slot0 = 0;
  }
  asm volatile("s_waitcnt vmcnt(5)" ::: "memory");
  doTile(ITERS - 2, slot0);
  if (++slot0 >= 3) slot0 = 0;
  asm volatile("s_waitcnt vmcnt(0)" ::: "memory");
  doTile(ITERS - 1, slot0);

  // finalize row mins: reduce MAX over the 16 column-lanes, dis = -2*max
  #pragma unroll
  for (int t = 0; t < 4; ++t)
    #pragma unroll
    for (int i = 0; i < 4; ++i) {
      float v = rowmax[t][i];
      v = fmaxf(v, __shfl_xor(v, 1));
      v = fmaxf(v, __shfl_xor(v, 2));
      v = fmaxf(v, __shfl_xor(v, 4));
      v = fmaxf(v, __shfl_xor(v, 8));
      if (l15 == 0)
        atomicMin(&rowmin[bN + r0 + t * 16 + q * 4 + i], encf(-2.f * v));
    }
}

// ---- reduction stage 1: 128 blocks x 256 thr ----
__global__ void reduce1_kernel(const unsigned int* __restrict__ rowmin,
                               const unsigned int* __restrict__ colmin,
                               float* __restrict__ partial) {
  __shared__ float sbuf[4];
  int i = blockIdx.x * 256 + threadIdx.x;
  float s = decf(rowmin[i]) + decf(colmin[i]);
  #pragma unroll
  for (int o = 32; o >= 1; o >>= 1) s += __shfl_xor(s, o);
  if ((threadIdx.x & 63) == 0) sbuf[threadIdx.x >> 6] = s;
  __syncthreads();
  if (threadIdx.x == 0)
    partial[blockIdx.x] = sbuf[0] + sbuf[1] + sbuf[2] + sbuf[3];
}

// ---- reduction stage 2: 1 block, 64 thr ----
__global__ void reduce2_kernel(const float* __restrict__ partial,
                               float* __restrict__ out) {
  float s = partial[threadIdx.x] + partial[threadIdx.x + 64];
  #pragma unroll
  for (int o = 32; o >= 1; o >>= 1) s += __shfl_xor(s, o);
  if (threadIdx.x == 0) out[0] = s / (float)TOTAL_ROWS;
}

extern "C" void kernel_launch(void* const* d_in, const int* in_sizes, int n_in,
                              void* d_out, int out_size, void* d_ws, size_t ws_size,
                              hipStream_t stream) {
  (void)in_sizes; (void)n_in; (void)out_size; (void)ws_size;
  const float* f  = (const float*)d_in[0];
  const float* f_ = (const float*)d_in[1];

  char* ws = (char*)d_ws;
  unsigned short* pk = (unsigned short*)ws;                        // 8 MiB packed bf16 f_
  float* gn2 = (float*)(ws + 8u * 1024u * 1024u);                  // 128 KiB
  unsigned int* rowmin = (unsigned int*)(gn2 + TOTAL_ROWS);        // 128 KiB
  unsigned int* colmin = rowmin + TOTAL_ROWS;                      // 128 KiB
  float* partial = (float*)(colmin + TOTAL_ROWS);                  // 512 B

  pack_b_kernel<<<2048, 256, 0, stream>>>(f_, pk, gn2);
  hipMemsetAsync(rowmin, 0xFF, (size_t)TOTAL_ROWS * 4, stream);
  hipMemsetAsync(colmin, 0xFF, (size_t)TOTAL_ROWS * 4, stream);
  chamfer_mfma_kernel<<<1024, 256, 0, stream>>>(f, pk, gn2, rowmin, colmin);
  reduce1_kernel<<<128, 256, 0, stream>>>(rowmin, colmin, partial);
  reduce2_kernel<<<1, 64, 0, stream>>>(partial, (float*)d_out);
}

// Round 8
// 88.895 us; speedup vs baseline: 1.5402x; 1.5402x over previous
//
#include <hip/hip_runtime.h>

#define BATCH 4
#define NPTS 8192
#define DIM 128
#define TOTAL_ROWS (BATCH * NPTS)   // 32768
#define SLICES 4                    // m-slices per batch
#define SLICE_W 2048                // cols per slice
#define ITERS 128                   // 16-col tiles per slice
#define TILES_PER_B 512             // NPTS/16
#define TILE_US 2048                // ushorts per packed 16-col tile (4 KB)

typedef __attribute__((ext_vector_type(8))) short bf16x8;
typedef __attribute__((ext_vector_type(4))) float f32x4;

// fp32 -> bf16 round-to-nearest-even
__device__ __forceinline__ unsigned short f2bf(float x) {
  unsigned u = __float_as_uint(x);
  u += 0x7FFFu + ((u >> 16) & 1u);
  return (unsigned short)(u >> 16);
}
// monotonic encoding of float for unsigned atomicMin (handles negatives)
__device__ __forceinline__ unsigned encf(float f) {
  unsigned b = __float_as_uint(f);
  return (b & 0x80000000u) ? ~b : (b | 0x80000000u);
}
__device__ __forceinline__ float decf(unsigned u) {
  unsigned b = (u & 0x80000000u) ? (u ^ 0x80000000u) : ~u;
  return __uint_as_float(b);
}

// ---- pack f_ into MFMA-fragment order (bf16) + row norms gn2 ----
// one block per 16-col tile; fragment uint4 index within tile = [kc|q|l15]
__global__ void pack_b_kernel(const float* __restrict__ in,
                              unsigned short* __restrict__ pk,
                              float* __restrict__ gn2) {
  __shared__ float sred[16][17];
  int tl  = threadIdx.x;
  int l15 = tl & 15, q = (tl >> 4) & 3, kc = tl >> 6;
  int tile = blockIdx.x;                 // b*512 + mtg
  int b = tile >> 9, mtg = tile & 511;
  const float* src = in + ((size_t)(b * NPTS + mtg * 16 + l15) * DIM) + kc * 32 + q * 8;
  float4 x = ((const float4*)src)[0], y = ((const float4*)src)[1];
  union { unsigned short us[8]; uint4 u4; } p;
  p.us[0] = f2bf(x.x); p.us[1] = f2bf(x.y); p.us[2] = f2bf(x.z); p.us[3] = f2bf(x.w);
  p.us[4] = f2bf(y.x); p.us[5] = f2bf(y.y); p.us[6] = f2bf(y.z); p.us[7] = f2bf(y.w);
  ((uint4*)(pk + (size_t)tile * TILE_US))[tl] = p.u4;
  float s = 0.f;
  s = fmaf(x.x, x.x, s); s = fmaf(x.y, x.y, s);
  s = fmaf(x.z, x.z, s); s = fmaf(x.w, x.w, s);
  s = fmaf(y.x, y.x, s); s = fmaf(y.y, y.y, s);
  s = fmaf(y.z, y.z, s); s = fmaf(y.w, y.w, s);
  sred[l15][(kc << 2) | q] = s;
  __syncthreads();
  if (tl < 16) {
    float t = 0.f;
    #pragma unroll
    for (int j = 0; j < 16; ++j) t += sred[tl][j];
    gn2[tile * 16 + tl] = t;             // row = b*NPTS + mtg*16 + tl
  }
}

// ---- main: per wave, 64 f-rows (A in regs) x 2048-col slice ----
// grid 512 = 2 blocks/CU; LB(256,2) => 256-reg budget, no spill
__global__ __launch_bounds__(256, 2)
void chamfer_mfma_kernel(const float* __restrict__ f,
                         const unsigned short* __restrict__ pk,
                         const float* __restrict__ gn2,
                         unsigned int* __restrict__ rowmin,
                         unsigned int* __restrict__ colmin) {
  const int lane = threadIdx.x & 63;
  const int l15  = lane & 15;
  const int q    = lane >> 4;                       // 0..3
  const int widx = threadIdx.x >> 6;                // 0..3

  // XCD-aware: 2 (b,slice) combos per XCD, 32 row-groups each
  const int bid   = blockIdx.x;                     // 0..511
  const int combo = (bid & 7) * 2 + ((bid >> 3) & 1);  // 0..15
  const int b     = combo >> 2;
  const int slice = combo & 3;
  const int rgrp  = bid >> 4;                       // 0..31
  const int r0    = rgrp * 256 + widx * 64;
  const int bN    = b * NPTS;
  const int tile0 = b * TILES_PER_B + slice * ITERS;

  // block-level column-min accumulator (encoded dis values)
  __shared__ unsigned cl[SLICE_W];
  #pragma unroll
  for (int k = 0; k < SLICE_W / 256; ++k)
    cl[threadIdx.x + k * 256] = 0xFFFFFFFFu;
  __syncthreads();

  // ---- A fragments (4 tiles x 4 k-chunks) + seeds h = -fn2/2, in-flight ----
  bf16x8 af[4][4];
  float h[4][4];
  const float* fb = f + (size_t)bN * DIM;
  #pragma unroll
  for (int t = 0; t < 4; ++t) {
    const float* frow = fb + (size_t)(r0 + t * 16 + l15) * DIM + q * 8;
    float s = 0.f;
    #pragma unroll
    for (int kc = 0; kc < 4; ++kc) {
      float4 x = *(const float4*)(frow + kc * 32);
      float4 y = *(const float4*)(frow + kc * 32 + 4);
      bf16x8 v;
      v[0] = (short)f2bf(x.x); v[1] = (short)f2bf(x.y);
      v[2] = (short)f2bf(x.z); v[3] = (short)f2bf(x.w);
      v[4] = (short)f2bf(y.x); v[5] = (short)f2bf(y.y);
      v[6] = (short)f2bf(y.z); v[7] = (short)f2bf(y.w);
      af[t][kc] = v;
      s = fmaf(x.x, x.x, s); s = fmaf(x.y, x.y, s);
      s = fmaf(x.z, x.z, s); s = fmaf(x.w, x.w, s);
      s = fmaf(y.x, y.x, s); s = fmaf(y.y, y.y, s);
      s = fmaf(y.z, y.z, s); s = fmaf(y.w, y.w, s);
    }
    s += __shfl_xor(s, 16); s += __shfl_xor(s, 32);   // lane holds fn2 of row (l&15)
    #pragma unroll
    for (int i = 0; i < 4; ++i) h[t][i] = -0.5f * __shfl(s, (q << 2) + i);
  }

  float rowmax[4][4];
  #pragma unroll
  for (int t = 0; t < 4; ++t)
    #pragma unroll
    for (int i = 0; i < 4; ++i) rowmax[t][i] = -3.4e38f;

  // packed fragment base for this wave's lane (contiguous 1KB per kc)
  const unsigned short* pkw = pk + (size_t)tile0 * TILE_US + lane * 8;
  const float*          gnb = gn2 + bN + slice * SLICE_W;

  auto loadB = [&](int mt, bf16x8 bfr[4], float& gv) {
    const unsigned short* base = pkw + (size_t)mt * TILE_US;
    #pragma unroll
    for (int kc = 0; kc < 4; ++kc) bfr[kc] = *(const bf16x8*)(base + kc * 512);
    gv = gnb[mt * 16 + l15];
  };

  auto compute = [&](const bf16x8 bfr[4], float gv, int mt) {
    const float g2 = -0.5f * gv;
    f32x4 acc[4];
    #pragma unroll
    for (int t = 0; t < 4; ++t) {
      f32x4 a;
      a[0] = h[t][0] + g2; a[1] = h[t][1] + g2;
      a[2] = h[t][2] + g2; a[3] = h[t][3] + g2;
      #pragma unroll
      for (int kc = 0; kc < 4; ++kc)
        a = __builtin_amdgcn_mfma_f32_16x16x32_bf16(af[t][kc], bfr[kc], a, 0, 0, 0);
      acc[t] = a;
    }
    // acc = dot - (fn2+gn2)/2 = -dis/2 ; min dis = -2*max acc
    float cm[4];
    #pragma unroll
    for (int t = 0; t < 4; ++t) {
      #pragma unroll
      for (int i = 0; i < 4; ++i)
        rowmax[t][i] = fmaxf(rowmax[t][i], acc[t][i]);
      cm[t] = fmaxf(fmaxf(acc[t][0], acc[t][1]), fmaxf(acc[t][2], acc[t][3]));
    }
    float cmax = fmaxf(fmaxf(cm[0], cm[1]), fmaxf(cm[2], cm[3]));
    // all 64 lanes: fire-and-forget LDS atomic (4-way same-address per col)
    atomicMin(&cl[mt * 16 + l15], encf(-2.f * cmax));
  };

  // 4-deep register pipeline, named buffers, compute-then-reload rotation
  bf16x8 b0[4], b1[4], b2[4], b3[4];
  float g0, g1, g2v, g3;
  loadB(0, b0, g0); loadB(1, b1, g1); loadB(2, b2, g2v); loadB(3, b3, g3);
  for (int mt = 0; mt < ITERS; mt += 4) {
    compute(b0, g0, mt);     loadB((mt + 4) & (ITERS - 1), b0, g0);
    compute(b1, g1, mt + 1); loadB((mt + 5) & (ITERS - 1), b1, g1);
    compute(b2, g2v, mt + 2); loadB((mt + 6) & (ITERS - 1), b2, g2v);
    compute(b3, g3, mt + 3); loadB((mt + 7) & (ITERS - 1), b3, g3);
  }

  // finalize row mins: reduce MAX over the 16 column-lanes, dis = -2*max
  #pragma unroll
  for (int t = 0; t < 4; ++t)
    #pragma unroll
    for (int i = 0; i < 4; ++i) {
      float v = rowmax[t][i];
      v = fmaxf(v, __shfl_xor(v, 1));
      v = fmaxf(v, __shfl_xor(v, 2));
      v = fmaxf(v, __shfl_xor(v, 4));
      v = fmaxf(v, __shfl_xor(v, 8));
      if (l15 == 0)
        atomicMin(&rowmin[bN + r0 + t * 16 + q * 4 + i], encf(-2.f * v));
    }

  // merge block-level col mins into global (one atomic per col per block)
  __syncthreads();
  #pragma unroll
  for (int k = 0; k < SLICE_W / 256; ++k) {
    int c = threadIdx.x + k * 256;
    atomicMin(&colmin[bN + slice * SLICE_W + c], cl[c]);
  }
}

// ---- reduction stage 1: 128 blocks x 256 thr ----
__global__ void reduce1_kernel(const unsigned int* __restrict__ rowmin,
                               const unsigned int* __restrict__ colmin,
                               float* __restrict__ partial) {
  __shared__ float sbuf[4];
  int i = blockIdx.x * 256 + threadIdx.x;
  float s = decf(rowmin[i]) + decf(colmin[i]);
  #pragma unroll
  for (int o = 32; o >= 1; o >>= 1) s += __shfl_xor(s, o);
  if ((threadIdx.x & 63) == 0) sbuf[threadIdx.x >> 6] = s;
  __syncthreads();
  if (threadIdx.x == 0)
    partial[blockIdx.x] = sbuf[0] + sbuf[1] + sbuf[2] + sbuf[3];
}

// ---- reduction stage 2: 1 block, 64 thr ----
__global__ void reduce2_kernel(const float* __restrict__ partial,
                               float* __restrict__ out) {
  float s = partial[threadIdx.x] + partial[threadIdx.x + 64];
  #pragma unroll
  for (int o = 32; o >= 1; o >>= 1) s += __shfl_xor(s, o);
  if (threadIdx.x == 0) out[0] = s / (float)TOTAL_ROWS;
}

extern "C" void kernel_launch(void* const* d_in, const int* in_sizes, int n_in,
                              void* d_out, int out_size, void* d_ws, size_t ws_size,
                              hipStream_t stream) {
  (void)in_sizes; (void)n_in; (void)out_size; (void)ws_size;
  const float* f  = (const float*)d_in[0];
  const float* f_ = (const float*)d_in[1];

  char* ws = (char*)d_ws;
  unsigned short* pk = (unsigned short*)ws;                        // 8 MiB packed bf16 f_
  float* gn2 = (float*)(ws + 8u * 1024u * 1024u);                  // 128 KiB
  unsigned int* rowmin = (unsigned int*)(gn2 + TOTAL_ROWS);        // 128 KiB
  unsigned int* colmin = rowmin + TOTAL_ROWS;                      // 128 KiB
  float* partial = (float*)(colmin + TOTAL_ROWS);                  // 512 B

  pack_b_kernel<<<2048, 256, 0, stream>>>(f_, pk, gn2);
  hipMemsetAsync(rowmin, 0xFF, (size_t)TOTAL_ROWS * 4, stream);
  hipMemsetAsync(colmin, 0xFF, (size_t)TOTAL_ROWS * 4, stream);
  chamfer_mfma_kernel<<<512, 256, 0, stream>>>(f, pk, gn2, rowmin, colmin);
  reduce1_kernel<<<128, 256, 0, stream>>>(rowmin, colmin, partial);
  reduce2_kernel<<<1, 64, 0, stream>>>(partial, (float*)d_out);
}